// Round 2
// baseline (11.491 us; speedup 1.0000x reference)
//
#include <hip/hip_runtime.h>
#include <hip/hip_bf16.h>

// Reference math: out = zeros(N_NODES, N_HYPER) @ Line_output + 0.0 * sigmoid(...).sum()
//               = exact zeros [20000, 128] (sigmoid sum finite; 0.0 * finite == 0.0).
// Entire kernel = write 2,560,000 float32 zeros (10.24 MB) to d_out each call.
//
// Round 1 showed 10.4 us total (~985 GB/s effective) -- launch/ramp dominated.
// This round: minimal-dispatch version. 625 blocks x 256 threads, each thread
// stores 4 coalesced float4 (64 B), block covers 64 KB, 625*64KB = 10.24 MB
// exactly. No grid-stride loop, no tail iterations for the exact size.

__global__ void __launch_bounds__(256) CrossLevel_zero_fill(float4* __restrict__ out4, int n4) {
    const float4 z = make_float4(0.f, 0.f, 0.f, 0.f);
    // Block covers 1024 consecutive float4s in 4 coalesced waves-of-stores.
    int base = blockIdx.x * 1024 + threadIdx.x;
#pragma unroll
    for (int j = 0; j < 4; ++j) {
        int i = base + j * 256;
        if (i < n4) out4[i] = z;
    }
}

__global__ void CrossLevel_zero_tail(float* __restrict__ out, int start, int n) {
    int i = start + blockIdx.x * blockDim.x + threadIdx.x;
    if (i < n) out[i] = 0.f;
}

extern "C" void kernel_launch(void* const* d_in, const int* in_sizes, int n_in,
                              void* d_out, int out_size, void* d_ws, size_t ws_size,
                              hipStream_t stream) {
    (void)d_in; (void)in_sizes; (void)n_in; (void)d_ws; (void)ws_size;
    float* out = (float*)d_out;
    int n = out_size;          // 2,560,000 floats
    int n4 = n / 4;            // 640,000 float4 stores
    int tail = n - n4 * 4;     // 0 for this problem

    int grid = (n4 + 1023) / 1024;   // 625 blocks
    if (grid < 1) grid = 1;
    CrossLevel_zero_fill<<<grid, 256, 0, stream>>>((float4*)out, n4);

    if (tail > 0) {
        CrossLevel_zero_tail<<<(tail + 255) / 256, 256, 0, stream>>>(out, n4 * 4, n);
    }
}